// Round 19
// baseline (444.418 us; speedup 1.0000x reference)
//
#include <hip/hip_runtime.h>
#include <hip/hip_bf16.h>
#include <math.h>

#define B_   8
#define CIN  32
#define COUT 64
#define KK_  4
#define DD   32
#define HH   64
#define WW   64
#define HW   (HH*WW)        // 4096
#define DHW  (DD*HH*WW)     // 131072

typedef __attribute__((ext_vector_type(8)))  short bf16x8;
typedef __attribute__((ext_vector_type(16))) float f32x16;

__device__ __forceinline__ unsigned short f2bf(float f) {
    union { float f; unsigned int u; } v; v.f = f;
    return (unsigned short)((v.u + 0x7FFFu + ((v.u >> 16) & 1u)) >> 16);   // RNE
}
__device__ __forceinline__ void gll16(const void* g, void* l) {
    __builtin_amdgcn_global_load_lds(
        (const __attribute__((address_space(1))) void*)g,
        (__attribute__((address_space(3))) void*)l, 16, 0, 0);
}

// ---------------- 1) transpose x -> bf16 xt rows + fused pooling partials ------
__global__ __launch_bounds__(256) void transpose_kernel(const float* __restrict__ x,
                                                        unsigned short* __restrict__ xt,
                                                        float* __restrict__ pblk) {
    const int t = threadIdx.x;
    const int r = t >> 6, w = t & 63;
    const int hb = blockIdx.x;
    const int h = (hb << 2) + r;
    const int d = blockIdx.y, b = blockIdx.z;

    const float* xb = x + (size_t)b*CIN*DHW + (size_t)d*HW + (size_t)h*WW + w;
    float f[CIN];
    #pragma unroll
    for (int c = 0; c < CIN; ++c) f[c] = xb[(size_t)c * DHW];

    unsigned int packed[CIN/2];
    #pragma unroll
    for (int c2 = 0; c2 < CIN/2; ++c2) {
        unsigned int lo = f2bf(f[2*c2]);
        unsigned int hi = f2bf(f[2*c2+1]);
        packed[c2] = lo | (hi << 16);
    }
    char* row = (char*)xt + (size_t)((b*DD + d)*HH + h) * 4096;
    #pragma unroll
    for (int q = 0; q < 4; ++q) {
        uint4 v = make_uint4(packed[4*q], packed[4*q+1], packed[4*q+2], packed[4*q+3]);
        *(uint4*)(row + q*1024 + (((w << 4)) ^ (q << 4))) = v;
    }

    #pragma unroll
    for (int off = 32; off > 0; off >>= 1) {
        #pragma unroll
        for (int c = 0; c < CIN; ++c) f[c] += __shfl_xor(f[c], off);
    }
    __shared__ float ws4[4][CIN];
    if ((t & 63) < CIN) ws4[r][t & 63] = f[t & 63];
    __syncthreads();
    if (t < CIN)
        pblk[(size_t)((b*DD + d)*16 + hb)*CIN + t] =
            ws4[0][t] + ws4[1][t] + ws4[2][t] + ws4[3][t];
}

// ---------------- 2) attention MLP + softmax + agg bias ----------------
__device__ __forceinline__ float gelu_erf(float v) {
    return 0.5f * v * (1.f + erff(v * 0.70710678118654752f));
}

__global__ void attn_kernel(const float* __restrict__ pblk,
                            const float* __restrict__ temperature,
                            const float* __restrict__ bn1_g, const float* __restrict__ bn1_b,
                            const float* __restrict__ w1,    const float* __restrict__ b1,
                            const float* __restrict__ bn2_g, const float* __restrict__ bn2_b,
                            const float* __restrict__ w2,    const float* __restrict__ b2,
                            const float* __restrict__ bn3_g, const float* __restrict__ bn3_b,
                            const float* __restrict__ w3,    const float* __restrict__ b3,
                            const float* __restrict__ cbias,
                            float* __restrict__ attn_out, float* __restrict__ aggb_out) {
    __shared__ float A[B_][CIN], A2[B_][CIN];
    __shared__ float L[B_][KK_], ATT[B_][KK_];
    const int t = threadIdx.x;
    const int b = t >> 5, c = t & 31;

    float pv = 0.f;
    for (int i = 0; i < DD*16; ++i) pv += pblk[(size_t)(b*DD*16 + i)*CIN + c];
    pv *= (1.f / (float)DHW);

    A[b][c] = gelu_erf(pv * bn1_g[c] + bn1_b[c]);
    __syncthreads();

    float s = b1[c];
    for (int j = 0; j < CIN; ++j) s += A[b][j] * w1[c*CIN + j];
    A2[b][c] = gelu_erf(s * bn2_g[c] + bn2_b[c]);
    __syncthreads();

    float s2 = b2[c];
    for (int j = 0; j < CIN; ++j) s2 += A2[b][j] * w2[c*CIN + j];
    s2 += pv;
    s2 = s2 * bn3_g[c] + bn3_b[c];
    __syncthreads();
    A[b][c] = s2;
    __syncthreads();

    if (c < KK_) {
        float lv = b3[c];
        for (int j = 0; j < CIN; ++j) lv += A[b][j] * w3[c*CIN + j];
        L[b][c] = lv;
    }
    __syncthreads();

    const float T = temperature[0];
    if (c < KK_) {
        float m = fmaxf(fmaxf(L[b][0], L[b][1]), fmaxf(L[b][2], L[b][3]));
        float e = expf((L[b][c] - m) / T);
        float den = 0.f;
        for (int j = 0; j < KK_; ++j) den += expf((L[b][j] - m) / T);
        float av = e / den;
        ATT[b][c] = av;
        attn_out[b*KK_ + c] = av;
    }
    __syncthreads();

    for (int o = c; o < COUT; o += CIN) {
        float sb = 0.f;
        for (int k = 0; k < KK_; ++k) sb += ATT[b][k] * cbias[k*COUT + o];
        aggb_out[b*COUT + o] = sb;
    }
}

// ---------------- 3) aggregate weights -> bf16 wt[b][kpos][co][ci] ----------------
__global__ void aggw_kernel(const float* __restrict__ weight,   // [K][O][CI][27]
                            const float* __restrict__ attn,     // [B][K]
                            unsigned short* __restrict__ wt) {  // [B][27][O][CI] bf16
    const int idx = blockIdx.x * 256 + threadIdx.x;
    const int ci   = idx & 31;
    const int co   = (idx >> 5) & 63;
    int r          = idx >> 11;
    const int kpos = r % 27;
    const int b    = r / 27;
    float s = 0.f;
    #pragma unroll
    for (int k = 0; k < KK_; ++k)
        s += attn[b*KK_ + k] * weight[((k*COUT + co)*CIN + ci)*27 + kpos];
    wt[idx] = f2bf(s);
}

// ---------------- 4) MFMA conv: persistent h-pair d-walk, 2 waves/SIMD -------------
// grid 256 (=1/CU): id = (hp<<3)|b  (b=id&7 pins b per XCD).
// block 512 = 8 waves (cv2 x wv2 x hv2); wave: 32co x 32w x 4d x 1h per step;
// walks 8 d-steps (all 32 d). LDS ring: 10 slabs x 4 ho-rows x 4 KiB = 160 KiB.
// All three budgets simultaneously: LDS 512 B/MFMA (75% ceiling), 2 waves/SIMD
// (sibling covers ds/A/store stalls), persistence (stage+store amortized).
__global__ __launch_bounds__(512, 2) void conv_mfma(const unsigned short* __restrict__ xt,
                                                    const unsigned short* __restrict__ wt,
                                                    const float* __restrict__ aggb,
                                                    float* __restrict__ out) {
    __shared__ char smem[163840];       // 10 slabs * 16384
    const int t    = threadIdx.x;
    const int lane = t & 63;
    const int wid  = t >> 6;            // 0..7
    const int hv   = wid & 1;
    const int wv   = (wid >> 1) & 1;
    const int cv   = wid >> 2;
    const int lw   = lane & 31, lh = lane >> 5;

    const int id = blockIdx.x;
    const int b  = id & 7;              // XCD-pinned
    const int hp = id >> 3;             // 0..31  (h-pair)
    const int h  = (hp << 1) + hv;

    const char* xb  = (const char*)xt + (size_t)(b*DD)*HH*4096;
    const char* wtb = (const char*)wt + (size_t)b * 27 * 4096 + (cv << 11);

    // stage one 4 KiB row: slab (zd mod 10), row ho (yh = hp*2-1+ho); wave-level
    auto stage_row = [&](int zd, int ho) {
        const int slot = (zd + 40) % 10;
        char* dst = smem + slot*16384 + (ho << 12);
        const int yh = (hp << 1) - 1 + ho;
        if ((unsigned)zd < DD && (unsigned)yh < HH) {
            const char* src = xb + ((size_t)(zd*HH + yh) << 12) + lane*16;
            #pragma unroll
            for (int q = 0; q < 4; ++q) gll16(src + (q << 10), dst + (q << 10));
        } else {
            #pragma unroll
            for (int q = 0; q < 4; ++q)
                *(uint4*)(dst + (q << 10) + lane*16) = make_uint4(0u,0u,0u,0u);
        }
    };

    // prologue: slabs zd=-1..4 (6 slabs x 4 rows = 24 rows, 3 per wave)
    #pragma unroll
    for (int i = 0; i < 3; ++i) {
        const int rid = wid*3 + i;      // 0..23
        stage_row((rid >> 2) - 1, rid & 3);
    }
    __syncthreads();

    // bias folded into accumulator init
    f32x16 binit;
    #pragma unroll
    for (int reg = 0; reg < 16; ++reg)
        binit[reg] = aggb[b*COUT + (cv << 5) + (reg & 3) + ((reg >> 2) << 3) + (lh << 2)];

    f32x16 acc[4];
    #pragma unroll
    for (int r = 0; r < 4; ++r) acc[r] = binit;

    const int a_off = lw*64 + lh*16;
    const int o0 = lh, o1 = 2 + lh;
    const bf16x8 bz = {};

    for (int s = 0; s < 8; ++s) {
        const int d0 = s << 2;
        if (s < 7) {
            // prefetch 4 slabs (d0+5..d0+8) x 4 rows = 16 rows, 2 per wave
            #pragma unroll
            for (int i = 0; i < 2; ++i) {
                const int rid = wid*2 + i;  // 0..15
                stage_row(d0 + 5 + (rid >> 2), rid & 3);
            }
        }
        // slab byte-bases for j = 0..5 (zd = d0-1+j)
        int rbj[6];
        #pragma unroll
        for (int j = 0; j < 6; ++j) rbj[j] = ((d0 - 1 + j + 40) % 10) * 16384;

        #pragma unroll
        for (int kh = 0; kh < 3; ++kh) {
            const int rowb = (hv + kh) << 12;    // row within slab
            // kh-resident A: 9 kpos x 2 K-halves
            bf16x8 av[9][2];
            #pragma unroll
            for (int kd = 0; kd < 3; ++kd)
                #pragma unroll
                for (int kw = 0; kw < 3; ++kw) {
                    const char* wk = wtb + (size_t)(((kd*3 + kh)*3 + kw) << 12);
                    av[kd*3 + kw][0] = *(const bf16x8*)(wk + a_off);
                    av[kd*3 + kw][1] = *(const bf16x8*)(wk + 32 + a_off);
                }

            #pragma unroll
            for (int kw = 0; kw < 3; ++kw) {
                const int wp  = (wv << 5) + lw + kw - 1;
                const bool oob = ((unsigned)wp >= (unsigned)WW);
                const int wpc = oob ? ((wp < 0) ? 0 : (WW - 1)) : wp;
                const int sw0 = (o0 << 10) + ((wpc << 4) ^ (o0 << 4));
                const int sw1 = (o1 << 10) + ((wpc << 4) ^ (o1 << 4));

                bf16x8 bc[6][2];
                #pragma unroll
                for (int j = 0; j < 6; ++j) {
                    bf16x8 v0 = *(const bf16x8*)&smem[rbj[j] + rowb + sw0];
                    bf16x8 v1 = *(const bf16x8*)&smem[rbj[j] + rowb + sw1];
                    bc[j][0] = oob ? bz : v0;
                    bc[j][1] = oob ? bz : v1;
                }

                __builtin_amdgcn_s_setprio(1);
                // kf-outer / r-inner: dependent MFMAs on acc[r] are 4 apart
                #pragma unroll
                for (int kf = 0; kf < 2; ++kf) {
                    #pragma unroll
                    for (int kd = 0; kd < 3; ++kd) {
                        #pragma unroll
                        for (int r = 0; r < 4; ++r) {
                            acc[r] = __builtin_amdgcn_mfma_f32_32x32x16_bf16(
                                av[kd*3 + kw][kf], bc[r + kd][kf], acc[r], 0, 0, 0);
                        }
                    }
                }
                __builtin_amdgcn_s_setprio(0);
            }
        }

        // tail: drain glls (long complete) + barrier BEFORE stores; stores fly
        // under next step's stage/compute.
        if (s < 7) {
            asm volatile("s_waitcnt vmcnt(0) lgkmcnt(0)" ::: "memory");
            __builtin_amdgcn_s_barrier();
        }

        const int sp0 = h*WW + (wv << 5) + lw;
        #pragma unroll
        for (int reg = 0; reg < 16; ++reg) {
            const int co = (cv << 5) + (reg & 3) + ((reg >> 2) << 3) + (lh << 2);
            float* oc = out + ((size_t)(b*COUT + co))*DHW + sp0;
            #pragma unroll
            for (int r = 0; r < 4; ++r)
                oc[(size_t)(d0 + r)*HW] = acc[r][reg];
        }
        #pragma unroll
        for (int r = 0; r < 4; ++r) acc[r] = binit;
    }
}

// ---------------- launch ----------------
extern "C" void kernel_launch(void* const* d_in, const int* in_sizes, int n_in,
                              void* d_out, int out_size, void* d_ws, size_t ws_size,
                              hipStream_t stream) {
    const float* x           = (const float*)d_in[0];
    const float* weight      = (const float*)d_in[1];
    const float* cbias       = (const float*)d_in[2];
    const float* temperature = (const float*)d_in[3];
    const float* bn1_g       = (const float*)d_in[4];
    const float* bn1_b       = (const float*)d_in[5];
    const float* w1          = (const float*)d_in[6];
    const float* b1          = (const float*)d_in[7];
    const float* bn2_g       = (const float*)d_in[8];
    const float* bn2_b       = (const float*)d_in[9];
    const float* w2          = (const float*)d_in[10];
    const float* b2          = (const float*)d_in[11];
    const float* bn3_g       = (const float*)d_in[12];
    const float* bn3_b       = (const float*)d_in[13];
    const float* w3          = (const float*)d_in[14];
    const float* b3          = (const float*)d_in[15];
    float* out = (float*)d_out;

    char* ws = (char*)d_ws;
    float*          attn = (float*)(ws + 1024);              // 32 f
    float*          aggb = (float*)(ws + 4096);              // 512 f
    float*          pblk = (float*)(ws + 65536);             // 8*512*32 f = 512 KiB
    unsigned short* wt   = (unsigned short*)(ws + 622592);   // 884736 B
    unsigned short* xt   = (unsigned short*)(ws + 1507328);  // 64 MiB

    transpose_kernel<<<dim3(HH/4, DD, B_), 256, 0, stream>>>(x, xt, pblk);
    attn_kernel<<<1, 256, 0, stream>>>(pblk, temperature,
                                       bn1_g, bn1_b, w1, b1,
                                       bn2_g, bn2_b, w2, b2,
                                       bn3_g, bn3_b, w3, b3,
                                       cbias, attn, aggb);
    aggw_kernel<<<(B_*27*COUT*CIN)/256, 256, 0, stream>>>(weight, attn, wt);
    conv_mfma<<<dim3(256), 512, 0, stream>>>(xt, wt, aggb, out);
}

// Round 21
// 178.038 us; speedup vs baseline: 2.4962x; 2.4962x over previous
//
#include <hip/hip_runtime.h>
#include <hip/hip_bf16.h>
#include <math.h>

#define B_   8
#define CIN  32
#define COUT 64
#define KK_  4
#define DD   32
#define HH   64
#define WW   64
#define HW   (HH*WW)        // 4096
#define DHW  (DD*HH*WW)     // 131072

typedef __attribute__((ext_vector_type(8)))  short bf16x8;
typedef __attribute__((ext_vector_type(16))) float f32x16;

__device__ __forceinline__ unsigned short f2bf(float f) {
    union { float f; unsigned int u; } v; v.f = f;
    return (unsigned short)((v.u + 0x7FFFu + ((v.u >> 16) & 1u)) >> 16);   // RNE
}
__device__ __forceinline__ void gll16(const void* g, void* l) {
    __builtin_amdgcn_global_load_lds(
        (const __attribute__((address_space(1))) void*)g,
        (__attribute__((address_space(3))) void*)l, 16, 0, 0);
}

// ---------------- 1) transpose x -> bf16 xt rows + fused pooling partials ------
__global__ __launch_bounds__(256) void transpose_kernel(const float* __restrict__ x,
                                                        unsigned short* __restrict__ xt,
                                                        float* __restrict__ pblk) {
    const int t = threadIdx.x;
    const int r = t >> 6, w = t & 63;
    const int hb = blockIdx.x;
    const int h = (hb << 2) + r;
    const int d = blockIdx.y, b = blockIdx.z;

    const float* xb = x + (size_t)b*CIN*DHW + (size_t)d*HW + (size_t)h*WW + w;
    float f[CIN];
    #pragma unroll
    for (int c = 0; c < CIN; ++c) f[c] = xb[(size_t)c * DHW];

    unsigned int packed[CIN/2];
    #pragma unroll
    for (int c2 = 0; c2 < CIN/2; ++c2) {
        unsigned int lo = f2bf(f[2*c2]);
        unsigned int hi = f2bf(f[2*c2+1]);
        packed[c2] = lo | (hi << 16);
    }
    char* row = (char*)xt + (size_t)((b*DD + d)*HH + h) * 4096;
    #pragma unroll
    for (int q = 0; q < 4; ++q) {
        uint4 v = make_uint4(packed[4*q], packed[4*q+1], packed[4*q+2], packed[4*q+3]);
        *(uint4*)(row + q*1024 + (((w << 4)) ^ (q << 4))) = v;
    }

    #pragma unroll
    for (int off = 32; off > 0; off >>= 1) {
        #pragma unroll
        for (int c = 0; c < CIN; ++c) f[c] += __shfl_xor(f[c], off);
    }
    __shared__ float ws4[4][CIN];
    if ((t & 63) < CIN) ws4[r][t & 63] = f[t & 63];
    __syncthreads();
    if (t < CIN)
        pblk[(size_t)((b*DD + d)*16 + hb)*CIN + t] =
            ws4[0][t] + ws4[1][t] + ws4[2][t] + ws4[3][t];
}

// ---------------- 2) attention MLP + softmax + agg bias ----------------
__device__ __forceinline__ float gelu_erf(float v) {
    return 0.5f * v * (1.f + erff(v * 0.70710678118654752f));
}

__global__ void attn_kernel(const float* __restrict__ pblk,
                            const float* __restrict__ temperature,
                            const float* __restrict__ bn1_g, const float* __restrict__ bn1_b,
                            const float* __restrict__ w1,    const float* __restrict__ b1,
                            const float* __restrict__ bn2_g, const float* __restrict__ bn2_b,
                            const float* __restrict__ w2,    const float* __restrict__ b2,
                            const float* __restrict__ bn3_g, const float* __restrict__ bn3_b,
                            const float* __restrict__ w3,    const float* __restrict__ b3,
                            const float* __restrict__ cbias,
                            float* __restrict__ attn_out, float* __restrict__ aggb_out) {
    __shared__ float A[B_][CIN], A2[B_][CIN];
    __shared__ float L[B_][KK_], ATT[B_][KK_];
    const int t = threadIdx.x;
    const int b = t >> 5, c = t & 31;

    float pv = 0.f;
    for (int i = 0; i < DD*16; ++i) pv += pblk[(size_t)(b*DD*16 + i)*CIN + c];
    pv *= (1.f / (float)DHW);

    A[b][c] = gelu_erf(pv * bn1_g[c] + bn1_b[c]);
    __syncthreads();

    float s = b1[c];
    for (int j = 0; j < CIN; ++j) s += A[b][j] * w1[c*CIN + j];
    A2[b][c] = gelu_erf(s * bn2_g[c] + bn2_b[c]);
    __syncthreads();

    float s2 = b2[c];
    for (int j = 0; j < CIN; ++j) s2 += A2[b][j] * w2[c*CIN + j];
    s2 += pv;
    s2 = s2 * bn3_g[c] + bn3_b[c];
    __syncthreads();
    A[b][c] = s2;
    __syncthreads();

    if (c < KK_) {
        float lv = b3[c];
        for (int j = 0; j < CIN; ++j) lv += A[b][j] * w3[c*CIN + j];
        L[b][c] = lv;
    }
    __syncthreads();

    const float T = temperature[0];
    if (c < KK_) {
        float m = fmaxf(fmaxf(L[b][0], L[b][1]), fmaxf(L[b][2], L[b][3]));
        float e = expf((L[b][c] - m) / T);
        float den = 0.f;
        for (int j = 0; j < KK_; ++j) den += expf((L[b][j] - m) / T);
        float av = e / den;
        ATT[b][c] = av;
        attn_out[b*KK_ + c] = av;
    }
    __syncthreads();

    for (int o = c; o < COUT; o += CIN) {
        float sb = 0.f;
        for (int k = 0; k < KK_; ++k) sb += ATT[b][k] * cbias[k*COUT + o];
        aggb_out[b*COUT + o] = sb;
    }
}

// ---------------- 3) aggregate weights -> bf16 wt[b][kpos][co][ci] ----------------
__global__ void aggw_kernel(const float* __restrict__ weight,   // [K][O][CI][27]
                            const float* __restrict__ attn,     // [B][K]
                            unsigned short* __restrict__ wt) {  // [B][27][O][CI] bf16
    const int idx = blockIdx.x * 256 + threadIdx.x;
    const int ci   = idx & 31;
    const int co   = (idx >> 5) & 63;
    int r          = idx >> 11;
    const int kpos = r % 27;
    const int b    = r / 27;
    float s = 0.f;
    #pragma unroll
    for (int k = 0; k < KK_; ++k)
        s += attn[b*KK_ + k] * weight[((k*COUT + co)*CIN + ci)*27 + kpos];
    wt[idx] = f2bf(s);
}

// ---------------- 4) MFMA conv: persistent 2-h d-walk, pinned A-resident -----------
// grid 256 (=1/CU): id = (h0<<3)|b  (b=id&7 pins b per XCD). Block 256 = 4 waves
// (cv2 x wv2); wave: 32co x 32w x 4d per step, 1h; walks 8 d-steps, then repeats
// for h0+32 (A-fragments h-invariant -> prologue A-preload amortized over both).
// A: 54 fragments pinned via asm "+v" -> phases have zero global loads.
// LDS: ring of 10 zd-slabs x 3 ho-rows x 4KB + zero row = 124 KiB, 1 block/CU.
__global__ __launch_bounds__(256, 1) void conv_mfma(const unsigned short* __restrict__ xt,
                                                    const unsigned short* __restrict__ wt,
                                                    const float* __restrict__ aggb,
                                                    float* __restrict__ out) {
    __shared__ char smem[126976];       // 10*12288 + 4096 zero row
    const int t    = threadIdx.x;
    const int lane = t & 63;
    const int wid  = t >> 6;            // 0..3
    const int cv   = wid >> 1;          // co-half
    const int wv   = wid & 1;           // w-half
    const int lw   = lane & 31, lh = lane >> 5;

    const int id = blockIdx.x;
    const int b  = id & 7;              // XCD-pinned
    const int h0 = id >> 3;             // 0..31

    const char* xb  = (const char*)xt + (size_t)(b*DD)*HH*4096;
    const char* wtb = (const char*)wt + (size_t)b * 27 * 4096 + (cv << 11);

    // ---- A preload: 27 kpos x 2 K-halves, then PIN so remat is impossible ----
    const int a_off = lw*64 + lh*16;
    bf16x8 avv[27][2];
    #pragma unroll
    for (int kp = 0; kp < 27; ++kp) {
        const char* wk = wtb + (size_t)(kp << 12);
        avv[kp][0] = *(const bf16x8*)(wk + a_off);
        avv[kp][1] = *(const bf16x8*)(wk + 32 + a_off);
    }
    #pragma unroll
    for (int kp = 0; kp < 27; ++kp) {
        asm volatile("" : "+v"(avv[kp][0]));
        asm volatile("" : "+v"(avv[kp][1]));
    }

    // bias accumulator template
    f32x16 binit;
    #pragma unroll
    for (int reg = 0; reg < 16; ++reg)
        binit[reg] = aggb[b*COUT + (cv << 5) + (reg & 3) + ((reg >> 2) << 3) + (lh << 2)];

    // zero row (offset 122880): 256 thr x 16B
    *(uint4*)&smem[122880 + t*16] = make_uint4(0u,0u,0u,0u);

    // stage slab zd into ring slot (3 ho rows, 12 KiB) for row h; wave-level
    auto stage_slab = [&](int zd, int slot, int h) {
        char* sb = smem + slot * 12288;
        #pragma unroll
        for (int ho = 0; ho < 3; ++ho) {
            const int yh = h - 1 + ho;
            char* dst = sb + (ho << 12);
            if ((unsigned)zd < DD && (unsigned)yh < HH) {
                const char* src = xb + ((size_t)(zd*HH + yh) << 12) + lane*16;
                #pragma unroll
                for (int q = 0; q < 4; ++q) gll16(src + (q << 10), dst + (q << 10));
            } else {
                #pragma unroll
                for (int q = 0; q < 4; ++q)
                    *(uint4*)(dst + (q << 10) + lane*16) = make_uint4(0u,0u,0u,0u);
            }
        }
    };

    const int o0 = lh, o1 = 2 + lh;
    const int ZR = 122880;
    bf16x8 bcp[2][12];
    f32x16 acc[4];

    for (int hseg = 0; hseg < 2; ++hseg) {
        const int h = h0 + (hseg << 5);

        if (hseg == 1) {
            // all waves must be past their hseg-0 reads before restaging the ring
            asm volatile("s_waitcnt vmcnt(0) lgkmcnt(0)" ::: "memory");
            __builtin_amdgcn_s_barrier();
        }
        // prologue: slabs zd=-1..4 -> slots 9,0,1,2,3,4
        for (int i = wid; i < 6; i += 4) stage_slab(i - 1, (i + 9) % 10, h);
        __syncthreads();

        #pragma unroll
        for (int r = 0; r < 4; ++r) acc[r] = binit;

        for (int s = 0; s < 8; ++s) {
            const int d0 = s << 2;
            if (s < 7) {
                const int zf = d0 + 5 + wid;           // fresh slabs 4s+5..4s+8
                stage_slab(zf, zf % 10, h);
            }
            // ring slot byte-bases for j = 0..5 (zd = d0-1+j)
            int rbj[6];
            #pragma unroll
            for (int j = 0; j < 6; ++j) rbj[j] = ((d0 + 9 + j) % 10) * 12288;

            auto loadB = [&](int p, int par) {
                const int kh = p / 3, kw = p % 3;
                const int wp  = (wv << 5) + lw + kw - 1;
                const bool oob = ((unsigned)wp >= (unsigned)WW);
                const int wpc = oob ? lw : wp;         // keep bank pattern on zero row
                const int sw0 = (o0 << 10) + ((wpc << 4) ^ (o0 << 4));
                const int sw1 = (o1 << 10) + ((wpc << 4) ^ (o1 << 4));
                #pragma unroll
                for (int j = 0; j < 6; ++j) {
                    const int base = oob ? ZR : rbj[j] + (kh << 12);
                    bcp[par][j*2+0] = *(const bf16x8*)&smem[base + sw0];
                    bcp[par][j*2+1] = *(const bf16x8*)&smem[base + sw1];
                }
            };

            loadB(0, 0);
            #pragma unroll
            for (int p = 0; p < 9; ++p) {
                const int cur = p & 1, nxt = cur ^ 1;
                if (p < 8) loadB(p + 1, nxt);
                __builtin_amdgcn_sched_barrier(0);     // prefetch issued before burst
                const int kh = p / 3, kw = p % 3;
                // khalf-outer / r-inner: dependent ops on acc[r] are 4 apart
                #pragma unroll
                for (int khalf = 0; khalf < 2; ++khalf) {
                    #pragma unroll
                    for (int kd = 0; kd < 3; ++kd) {
                        const int kp = (kd*3 + kh)*3 + kw;
                        #pragma unroll
                        for (int r = 0; r < 4; ++r) {
                            acc[r] = __builtin_amdgcn_mfma_f32_32x32x16_bf16(
                                avv[kp][khalf], bcp[cur][(r + kd)*2 + khalf], acc[r], 0, 0, 0);
                        }
                    }
                }
            }

            // tail: drain glls + barrier BEFORE stores; stores fly under next step
            if (s < 7) {
                asm volatile("s_waitcnt vmcnt(0) lgkmcnt(0)" ::: "memory");
                __builtin_amdgcn_s_barrier();
            }

            const int sp0 = h*WW + (wv << 5) + lw;
            #pragma unroll
            for (int reg = 0; reg < 16; ++reg) {
                const int co = (cv << 5) + (reg & 3) + ((reg >> 2) << 3) + (lh << 2);
                float* oc = out + ((size_t)(b*COUT + co))*DHW + sp0;
                #pragma unroll
                for (int r = 0; r < 4; ++r)
                    oc[(size_t)(d0 + r)*HW] = acc[r][reg];
            }
            #pragma unroll
            for (int r = 0; r < 4; ++r) acc[r] = binit;
        }
    }
}

// ---------------- launch ----------------
extern "C" void kernel_launch(void* const* d_in, const int* in_sizes, int n_in,
                              void* d_out, int out_size, void* d_ws, size_t ws_size,
                              hipStream_t stream) {
    const float* x           = (const float*)d_in[0];
    const float* weight      = (const float*)d_in[1];
    const float* cbias       = (const float*)d_in[2];
    const float* temperature = (const float*)d_in[3];
    const float* bn1_g       = (const float*)d_in[4];
    const float* bn1_b       = (const float*)d_in[5];
    const float* w1          = (const float*)d_in[6];
    const float* b1          = (const float*)d_in[7];
    const float* bn2_g       = (const float*)d_in[8];
    const float* bn2_b       = (const float*)d_in[9];
    const float* w2          = (const float*)d_in[10];
    const float* b2          = (const float*)d_in[11];
    const float* bn3_g       = (const float*)d_in[12];
    const float* bn3_b       = (const float*)d_in[13];
    const float* w3          = (const float*)d_in[14];
    const float* b3          = (const float*)d_in[15];
    float* out = (float*)d_out;

    char* ws = (char*)d_ws;
    float*          attn = (float*)(ws + 1024);              // 32 f
    float*          aggb = (float*)(ws + 4096);              // 512 f
    float*          pblk = (float*)(ws + 65536);             // 8*512*32 f = 512 KiB
    unsigned short* wt   = (unsigned short*)(ws + 622592);   // 884736 B
    unsigned short* xt   = (unsigned short*)(ws + 1507328);  // 64 MiB

    transpose_kernel<<<dim3(HH/4, DD, B_), 256, 0, stream>>>(x, xt, pblk);
    attn_kernel<<<1, 256, 0, stream>>>(pblk, temperature,
                                       bn1_g, bn1_b, w1, b1,
                                       bn2_g, bn2_b, w2, b2,
                                       bn3_g, bn3_b, w3, b3,
                                       cbias, attn, aggb);
    aggw_kernel<<<(B_*27*COUT*CIN)/256, 256, 0, stream>>>(weight, attn, wt);
    conv_mfma<<<dim3(256), 256, 0, stream>>>(xt, wt, aggb, out);
}